// Round 1
// baseline (151.784 us; speedup 1.0000x reference)
//
#include <hip/hip_runtime.h>
#include <hip/hip_bf16.h>

// Round 8 = r7 structure with conflict-free subtiled LDS layouts.
// r7's SQ_LDS_BANK_CONFLICT = 8388608 = exactly 4 * (#V ds_read_b64)
// = exactly 8 * (#K ds_read_b128): both the padded-row K reads (144B
// stride -> 8 start banks for 64 lanes) and the XOR-granule V reads
// (4-way) were conflicted, ~17% of kernel cycles.
// New layouts make every fragment-read instruction cover a contiguous
// bijective LDS window (the provably conflict-free pattern):
//  - K: 8 subtiles [16 key][32 d] (1KB);  ds_read_b128 window = 1 subtile
//  - V^T: 16 subtiles [16 d][16 k] (512B); ds_read_b64 window = 1 subtile,
//    16B-pair XOR on (d>>3)&1 keeps the staging ds_write_b128 spread
//    across all 8 bank slots.
// All 24 reads/tile: one thread-constant base + compile-time immediate
// offsets (kills the per-read XOR/addr VALU in the PV loop).
// Everything else identical to r7: BQ=128 (16q/wave), 8 waves, grid 512
// (2 blk/CU), LDS double-buffer, reg prefetch, 1 barrier/tile, mask folded
// into QK MFMA C-init, scale folded into Q conversion, fixed-base softmax.

typedef __attribute__((ext_vector_type(8))) short bf16x8;
typedef __attribute__((ext_vector_type(4))) short bf16x4;
typedef __attribute__((ext_vector_type(4))) float f32x4;

#define B_ 2
#define S_ 2048
#define H_ 16
#define D_ 64
#define BQ 128
#define BK 64
#define NT (S_ / BK)
#define ROWSZ (H_ * D_)        // 1024 floats between s rows

#define LOG2E  1.44269504088896340736f
#define SCALE2 (0.125f * LOG2E)

__device__ __forceinline__ unsigned pack2(float a, float b) {
    union { __hip_bfloat162 h; unsigned u; } x;
    x.h = __float22bfloat162_rn(make_float2(a, b));   // v_cvt_pk_bf16_f32
    return x.u;
}

__device__ __forceinline__ float fexp2(float x) {
#if __has_builtin(__builtin_amdgcn_exp2f)
    return __builtin_amdgcn_exp2f(x);
#else
    return __expf(x * 0.69314718055994531f);
#endif
}

__device__ __forceinline__ f32x4 mfma16(bf16x4 a, bf16x4 b, f32x4 c) {
#if __has_builtin(__builtin_amdgcn_mfma_f32_16x16x16bf16_1k)
    return __builtin_amdgcn_mfma_f32_16x16x16bf16_1k(a, b, c, 0, 0, 0);
#else
    bf16x8 a8 = {a[0], a[1], a[2], a[3], 0, 0, 0, 0};
    bf16x8 b8 = {b[0], b[1], b[2], b[3], 0, 0, 0, 0};
    return __builtin_amdgcn_mfma_f32_16x16x32_bf16(a8, b8, c, 0, 0, 0);
#endif
}

__global__ __launch_bounds__(512, 4)
void fattn_kernel(const float* __restrict__ qg,
                  const float* __restrict__ kg,
                  const float* __restrict__ vg,
                  const float* __restrict__ maskg,
                  float* __restrict__ outg)
{
    // K: addr(key,d) = ((key>>4)*2 + (d>>5))*512 + (key&15)*32 + (d&31)
    __shared__ __attribute__((aligned(16))) ushort Ks[2][4096];
    // V^T: addr(d,k) = ((k>>4)*4 + (d>>4))*256 + (d&15)*16
    //                + ((((k>>3)&1) ^ ((d>>3)&1)))*8 + (k&7)
    __shared__ __attribute__((aligned(16))) ushort Vt[2][4096];
    __shared__ __attribute__((aligned(16))) float  Em[S_];   // mask * log2e

    const int qt = blockIdx.x, h = blockIdx.y, b = blockIdx.z;
    const int tid = threadIdx.x;
    const int w = tid >> 6, lane = tid & 63, g = lane >> 4, l15 = lane & 15;

    // ---- stage pre-scaled mask to LDS (once) ----
    {
        float4 mv = *(const float4*)(maskg + (size_t)b * S_ + tid * 4);
        *(float4*)&Em[tid * 4] = make_float4(mv.x * LOG2E, mv.y * LOG2E,
                                             mv.z * LOG2E, mv.w * LOG2E);
    }

    // ---- Q fragment (B-operand, x32), scale folded in ----
    const int qrow = qt * BQ + w * 16 + l15;
    const float* qp = qg + (size_t)(b * S_ + qrow) * ROWSZ + h * D_;
    bf16x8 qf[2];
#pragma unroll
    for (int half = 0; half < 2; ++half) {
        float4 f0 = *(const float4*)(qp + half * 32 + g * 8);
        float4 f1 = *(const float4*)(qp + half * 32 + g * 8 + 4);
        union { bf16x8 v; uint4 u; } x;
        x.u = make_uint4(pack2(f0.x * SCALE2, f0.y * SCALE2),
                         pack2(f0.z * SCALE2, f0.w * SCALE2),
                         pack2(f1.x * SCALE2, f1.y * SCALE2),
                         pack2(f1.z * SCALE2, f1.w * SCALE2));
        qf[half] = x.v;
    }

    // ---- staging maps (all LDS write addrs thread-constant) ----
    const int skey = tid >> 4;            // 0..31 (and +32 second pass)
    const int sd   = (tid & 15) * 4;      // K d-offset (floats)
    // K write: subtile ((skey>>4)*2 + (sd>>5)), row skey&15, col sd&31
    const int kw0 = ((skey >> 4) * 2 + (sd >> 5)) * 512
                  + (skey & 15) * 32 + (sd & 31);
    const int kw1 = kw0 + 4 * 512;        // keys +32 -> subtile +4
    // V write: d = lane, keys w*8..w*8+7 -> one 16B granule, pair-XORed
    const int vw = ((w >> 1) * 4 + (lane >> 4)) * 256 + (lane & 15) * 16
                 + (((w & 1) ^ ((lane >> 3) & 1)) << 3);

    const size_t kvbase = (size_t)b * S_ * ROWSZ + h * D_;

    float4 kpre0, kpre1;
    float  vpre[8];
    auto prefetch = [&](int kt) {
        const float* kb = kg + kvbase + (size_t)kt * BK * ROWSZ;
        kpre0 = *(const float4*)(kb + (size_t)skey * ROWSZ + sd);
        kpre1 = *(const float4*)(kb + (size_t)(skey + 32) * ROWSZ + sd);
        const float* vb = vg + kvbase + (size_t)kt * BK * ROWSZ + lane;
#pragma unroll
        for (int i = 0; i < 8; ++i) vpre[i] = vb[(size_t)(w * 8 + i) * ROWSZ];
    };
    auto stage = [&](int buf) {
        *(uint2*)&Ks[buf][kw0] =
            make_uint2(pack2(kpre0.x, kpre0.y), pack2(kpre0.z, kpre0.w));
        *(uint2*)&Ks[buf][kw1] =
            make_uint2(pack2(kpre1.x, kpre1.y), pack2(kpre1.z, kpre1.w));
        *(uint4*)&Vt[buf][vw] =
            make_uint4(pack2(vpre[0], vpre[1]), pack2(vpre[2], vpre[3]),
                       pack2(vpre[4], vpre[5]), pack2(vpre[6], vpre[7]));
    };

    float l_r = 0.0f;                   // per-lane (q=l15) partial denominator
    f32x4 o_acc[4];
#pragma unroll
    for (int t = 0; t < 4; ++t) o_acc[t] = (f32x4){0.f, 0.f, 0.f, 0.f};

    prefetch(0);
    stage(0);
    __syncthreads();                    // also covers Em staging

    // ---- read bases (thread-constant; all reads at immediate offsets) ----
    const int krd = l15 * 32 + g * 8;                     // K subtile window
    const int vrd = l15 * 16 + ((((g >> 1) ^ (l15 >> 3)) & 1) << 3)
                  + (g & 1) * 4;                          // V subtile window

    for (int kt = 0; kt < NT; ++kt) {
        const int cur = kt & 1;
        if (kt + 1 < NT) prefetch(kt + 1);   // loads in flight across compute

        // ---- St = K Q^T + mask (C-init) : St[key=t*16+g*4+r][q=l15] ----
        const ushort* ks = Ks[cur];
        float sv[4][4];
#pragma unroll
        for (int t = 0; t < 4; ++t) {
            f32x4 acc = *(const f32x4*)&Em[kt * BK + t * 16 + g * 4];  // bcast
            bf16x8 kf0 = *(const bf16x8*)&ks[t * 1024 + krd];
            bf16x8 kf1 = *(const bf16x8*)&ks[t * 1024 + 512 + krd];
            acc = __builtin_amdgcn_mfma_f32_16x16x32_bf16(kf0, qf[0], acc, 0, 0, 0);
            acc = __builtin_amdgcn_mfma_f32_16x16x32_bf16(kf1, qf[1], acc, 0, 0, 0);
            sv[t][0] = acc[0]; sv[t][1] = acc[1]; sv[t][2] = acc[2]; sv[t][3] = acc[3];
        }

        // ---- fixed-base softmax: p = exp2(s); l += sum (no max, no rescale) ----
        float rs = 0.f;
#pragma unroll
        for (int t = 0; t < 4; ++t)
#pragma unroll
            for (int r = 0; r < 4; ++r) {
                float p = fexp2(sv[t][r]);
                sv[t][r] = p;
                rs += p;
            }
        l_r += rs;

        // ---- P^T fragments direct from regs (St C-layout == x16 B-layout) ----
        bf16x4 pf[4];
#pragma unroll
        for (int c = 0; c < 4; ++c) {
            union { bf16x4 v; uint2 u; } x;
            x.u = make_uint2(pack2(sv[c][0], sv[c][1]), pack2(sv[c][2], sv[c][3]));
            pf[c] = x.v;
        }

        // ---- O^T += V^T P^T : conflict-free b64 reads at immediate offsets,
        //      c-outer/t2-inner = 4 independent accumulator chains ----
        const ushort* vt = Vt[cur];
#pragma unroll
        for (int c = 0; c < 4; ++c)
#pragma unroll
            for (int t2 = 0; t2 < 4; ++t2) {
                bf16x4 vf = *(const bf16x4*)&vt[(c * 4 + t2) * 256 + vrd];
                o_acc[t2] = mfma16(vf, pf[c], o_acc[t2]);
            }

        if (kt + 1 < NT) stage(cur ^ 1);    // vmcnt drain lands post-compute
        __syncthreads();                    // single barrier per tile
    }

    // ---- epilogue: reduce l across the 4 quads, normalize, store fp32 ----
    l_r += __shfl_xor(l_r, 16);
    l_r += __shfl_xor(l_r, 32);
    const float inv = 1.0f / l_r;
    float* op = outg + (size_t)(b * S_ + qrow) * ROWSZ + h * D_;
#pragma unroll
    for (int t2 = 0; t2 < 4; ++t2)
#pragma unroll
        for (int r = 0; r < 4; ++r)
            op[t2 * 16 + g * 4 + r] = o_acc[t2][r] * inv;
}

extern "C" void kernel_launch(void* const* d_in, const int* in_sizes, int n_in,
                              void* d_out, int out_size, void* d_ws, size_t ws_size,
                              hipStream_t stream) {
    dim3 grid(S_ / BQ, H_, B_);   // (16,16,2) = 512 blocks, 2/CU
    fattn_kernel<<<grid, dim3(512), 0, stream>>>(
        (const float*)d_in[0], (const float*)d_in[1], (const float*)d_in[2],
        (const float*)d_in[3], (float*)d_out);
}

// Round 3
// 144.919 us; speedup vs baseline: 1.0474x; 1.0474x over previous
//
#include <hip/hip_runtime.h>
#include <hip/hip_bf16.h>

// Round 9 (resubmit; r2 bench was a GPUAcquisitionTimeout, never ran).
// r7 structure with LDS layouts redesigned against the *measured*
// conflict model. Calibration from r7/r8 counters:
//   r7: 8388608  = V-reads(2097152) x 4   -> V read was 2-way; K read (144B
//       padded stride) was CONFLICT-FREE.
//   r8: 14680064 = V x 4 + K-reads(1048576) x 6 -> subtiled K read was 4-way.
// Model: LDS serves a wave access in 128B phases over ALIGNED LANE GROUPS
// (8 lanes for b128, 16 for b64). Conflict-free <=> each group's byte
// addresses mod 128 cover all 32 banks exactly once.
// New layouts satisfy this for ALL SIX access patterns (K read b128,
// K write b64, V read b64, V write b64, Em read/write):
//  K : addr = t*1024 + ((d>>3)+(klocal>>3)*8)*64 + ((klocal&7)^(d>>3))*8 + (d&7)
//      read slot  = (l15&7)^dblk  -> 8 distinct per 8-lane group
//      write slot = (skey&7)^(l15>>1), half = l15&1 -> 16 distinct per group
//  V^T: addr = ((k>>4)*4+(d>>4))*256 + ((k>>2)&3)*64 + (d&15)*4 + (k&3)
//      read/write slot = l15*8 -> 16 distinct per 16-lane group
// All fragment reads: thread-constant base + compile-time immediate offsets.
// Everything else identical to r7: BQ=128 (16q/wave), 8 waves, grid 512
// (2 blk/CU), LDS double-buffer, reg prefetch, 1 barrier/tile, mask folded
// into QK MFMA C-init, scale folded into Q conversion, fixed-base softmax.

typedef __attribute__((ext_vector_type(8))) short bf16x8;
typedef __attribute__((ext_vector_type(4))) short bf16x4;
typedef __attribute__((ext_vector_type(4))) float f32x4;

#define B_ 2
#define S_ 2048
#define H_ 16
#define D_ 64
#define BQ 128
#define BK 64
#define NT (S_ / BK)
#define ROWSZ (H_ * D_)        // 1024 floats between s rows

#define LOG2E  1.44269504088896340736f
#define SCALE2 (0.125f * LOG2E)

__device__ __forceinline__ unsigned pack2(float a, float b) {
    union { __hip_bfloat162 h; unsigned u; } x;
    x.h = __float22bfloat162_rn(make_float2(a, b));   // v_cvt_pk_bf16_f32
    return x.u;
}

__device__ __forceinline__ float fexp2(float x) {
#if __has_builtin(__builtin_amdgcn_exp2f)
    return __builtin_amdgcn_exp2f(x);
#else
    return __expf(x * 0.69314718055994531f);
#endif
}

__device__ __forceinline__ f32x4 mfma16(bf16x4 a, bf16x4 b, f32x4 c) {
#if __has_builtin(__builtin_amdgcn_mfma_f32_16x16x16bf16_1k)
    return __builtin_amdgcn_mfma_f32_16x16x16bf16_1k(a, b, c, 0, 0, 0);
#else
    bf16x8 a8 = {a[0], a[1], a[2], a[3], 0, 0, 0, 0};
    bf16x8 b8 = {b[0], b[1], b[2], b[3], 0, 0, 0, 0};
    return __builtin_amdgcn_mfma_f32_16x16x32_bf16(a8, b8, c, 0, 0, 0);
#endif
}

__global__ __launch_bounds__(512, 4)
void fattn_kernel(const float* __restrict__ qg,
                  const float* __restrict__ kg,
                  const float* __restrict__ vg,
                  const float* __restrict__ maskg,
                  float* __restrict__ outg)
{
    __shared__ __attribute__((aligned(16))) ushort Ks[2][4096];
    __shared__ __attribute__((aligned(16))) ushort Vt[2][4096];
    __shared__ __attribute__((aligned(16))) float  Em[S_];   // mask * log2e

    const int qt = blockIdx.x, h = blockIdx.y, b = blockIdx.z;
    const int tid = threadIdx.x;
    const int w = tid >> 6, lane = tid & 63, g = lane >> 4, l15 = lane & 15;

    // ---- stage pre-scaled mask to LDS (once) ----
    {
        float4 mv = *(const float4*)(maskg + (size_t)b * S_ + tid * 4);
        *(float4*)&Em[tid * 4] = make_float4(mv.x * LOG2E, mv.y * LOG2E,
                                             mv.z * LOG2E, mv.w * LOG2E);
    }

    // ---- Q fragment (B-operand, x32), scale folded in ----
    const int qrow = qt * BQ + w * 16 + l15;
    const float* qp = qg + (size_t)(b * S_ + qrow) * ROWSZ + h * D_;
    bf16x8 qf[2];
#pragma unroll
    for (int half = 0; half < 2; ++half) {
        float4 f0 = *(const float4*)(qp + half * 32 + g * 8);
        float4 f1 = *(const float4*)(qp + half * 32 + g * 8 + 4);
        union { bf16x8 v; uint4 u; } x;
        x.u = make_uint4(pack2(f0.x * SCALE2, f0.y * SCALE2),
                         pack2(f0.z * SCALE2, f0.w * SCALE2),
                         pack2(f1.x * SCALE2, f1.y * SCALE2),
                         pack2(f1.z * SCALE2, f1.w * SCALE2));
        qf[half] = x.v;
    }

    // ---- staging maps (all LDS write addrs thread-constant) ----
    const int skey = tid >> 4;            // 0..31 (and +32 second pass)
    const int sd   = (tid & 15) * 4;      // K d-offset (floats)
    // K write: t=(skey>>4), row=(sd>>3)+((skey>>3)&1)*8, slot=(skey&7)^(sd>>3)
    const int kw0 = (skey >> 4) * 1024
                  + ((sd >> 3) + ((skey >> 3) & 1) * 8) * 64
                  + (((skey & 7) ^ (sd >> 3)) << 3) + (sd & 7);
    const int kw1 = kw0 + 2048;           // keys +32 -> t+2
    // V write: d = lane, keys w*8..w*8+7 = two 8B granules (kb=2w, 2w+1)
    const int vwA = ((w >> 1) * 4 + (lane >> 4)) * 256
                  + ((2 * w) & 3) * 64 + (lane & 15) * 4;
    const int vwB = vwA + 64;

    const size_t kvbase = (size_t)b * S_ * ROWSZ + h * D_;

    float4 kpre0, kpre1;
    float  vpre[8];
    auto prefetch = [&](int kt) {
        const float* kb = kg + kvbase + (size_t)kt * BK * ROWSZ;
        kpre0 = *(const float4*)(kb + (size_t)skey * ROWSZ + sd);
        kpre1 = *(const float4*)(kb + (size_t)(skey + 32) * ROWSZ + sd);
        const float* vb = vg + kvbase + (size_t)kt * BK * ROWSZ + lane;
#pragma unroll
        for (int i = 0; i < 8; ++i) vpre[i] = vb[(size_t)(w * 8 + i) * ROWSZ];
    };
    auto stage = [&](int buf) {
        *(uint2*)&Ks[buf][kw0] =
            make_uint2(pack2(kpre0.x, kpre0.y), pack2(kpre0.z, kpre0.w));
        *(uint2*)&Ks[buf][kw1] =
            make_uint2(pack2(kpre1.x, kpre1.y), pack2(kpre1.z, kpre1.w));
        *(uint2*)&Vt[buf][vwA] =
            make_uint2(pack2(vpre[0], vpre[1]), pack2(vpre[2], vpre[3]));
        *(uint2*)&Vt[buf][vwB] =
            make_uint2(pack2(vpre[4], vpre[5]), pack2(vpre[6], vpre[7]));
    };

    float l_r = 0.0f;                   // per-lane (q=l15) partial denominator
    f32x4 o_acc[4];
#pragma unroll
    for (int t = 0; t < 4; ++t) o_acc[t] = (f32x4){0.f, 0.f, 0.f, 0.f};

    prefetch(0);
    stage(0);
    __syncthreads();                    // also covers Em staging

    // ---- read bases (thread-constant; reads at immediate offsets) ----
    // K frag (d-half 0/1): row = dblk + (l15>>3)*8, slot = (l15&7)^dblk
    const int krd0 = (g + (l15 >> 3) * 8) * 64 + (((l15 & 7) ^ g) << 3);
    const int krd1 = (g + 4 + (l15 >> 3) * 8) * 64 + (((l15 & 7) ^ (g + 4)) << 3);
    // V frag: subtile (c*4+t2), kb = g, d = l15
    const int vrd = g * 64 + l15 * 4;

    for (int kt = 0; kt < NT; ++kt) {
        const int cur = kt & 1;
        if (kt + 1 < NT) prefetch(kt + 1);   // loads in flight across compute

        // ---- St = K Q^T + mask (C-init) : St[key=t*16+g*4+r][q=l15] ----
        const ushort* ks = Ks[cur];
        float sv[4][4];
#pragma unroll
        for (int t = 0; t < 4; ++t) {
            f32x4 acc = *(const f32x4*)&Em[kt * BK + t * 16 + g * 4];  // bcast
            bf16x8 kf0 = *(const bf16x8*)&ks[t * 1024 + krd0];
            bf16x8 kf1 = *(const bf16x8*)&ks[t * 1024 + krd1];
            acc = __builtin_amdgcn_mfma_f32_16x16x32_bf16(kf0, qf[0], acc, 0, 0, 0);
            acc = __builtin_amdgcn_mfma_f32_16x16x32_bf16(kf1, qf[1], acc, 0, 0, 0);
            sv[t][0] = acc[0]; sv[t][1] = acc[1]; sv[t][2] = acc[2]; sv[t][3] = acc[3];
        }

        // ---- fixed-base softmax: p = exp2(s); l += sum (no max, no rescale) ----
        float rs = 0.f;
#pragma unroll
        for (int t = 0; t < 4; ++t)
#pragma unroll
            for (int r = 0; r < 4; ++r) {
                float p = fexp2(sv[t][r]);
                sv[t][r] = p;
                rs += p;
            }
        l_r += rs;

        // ---- P^T fragments direct from regs (St C-layout == x16 B-layout) ----
        bf16x4 pf[4];
#pragma unroll
        for (int c = 0; c < 4; ++c) {
            union { bf16x4 v; uint2 u; } x;
            x.u = make_uint2(pack2(sv[c][0], sv[c][1]), pack2(sv[c][2], sv[c][3]));
            pf[c] = x.v;
        }

        // ---- O^T += V^T P^T : conflict-free b64 reads at immediate offsets,
        //      c-outer/t2-inner = 4 independent accumulator chains ----
        const ushort* vt = Vt[cur];
#pragma unroll
        for (int c = 0; c < 4; ++c)
#pragma unroll
            for (int t2 = 0; t2 < 4; ++t2) {
                bf16x4 vf = *(const bf16x4*)&vt[(c * 4 + t2) * 256 + vrd];
                o_acc[t2] = mfma16(vf, pf[c], o_acc[t2]);
            }

        if (kt + 1 < NT) stage(cur ^ 1);    // vmcnt drain lands post-compute
        __syncthreads();                    // single barrier per tile
    }

    // ---- epilogue: reduce l across the 4 quads, normalize, store fp32 ----
    l_r += __shfl_xor(l_r, 16);
    l_r += __shfl_xor(l_r, 32);
    const float inv = 1.0f / l_r;
    float* op = outg + (size_t)(b * S_ + qrow) * ROWSZ + h * D_;
#pragma unroll
    for (int t2 = 0; t2 < 4; ++t2)
#pragma unroll
        for (int r = 0; r < 4; ++r)
            op[t2 * 16 + g * 4 + r] = o_acc[t2][r] * inv;
}

extern "C" void kernel_launch(void* const* d_in, const int* in_sizes, int n_in,
                              void* d_out, int out_size, void* d_ws, size_t ws_size,
                              hipStream_t stream) {
    dim3 grid(S_ / BQ, H_, B_);   // (16,16,2) = 512 blocks, 2/CU
    fattn_kernel<<<grid, dim3(512), 0, stream>>>(
        (const float*)d_in[0], (const float*)d_in[1], (const float*)d_in[2],
        (const float*)d_in[3], (float*)d_out);
}